// Round 13
// baseline (2089.896 us; speedup 1.0000x reference)
//
#include <hip/hip_runtime.h>

#define B 4
#define N 8192
#define H 256
#define E 8192
#define M 2048
#define T_ITERS 8
#define ET 4

typedef __bf16 bf16x8 __attribute__((ext_vector_type(8)));
typedef _Float16 f16x8 __attribute__((ext_vector_type(8)));
typedef float f32x4 __attribute__((ext_vector_type(4)));

__device__ __forceinline__ unsigned short f2bf(float x) {
    unsigned u = __float_as_uint(x);
    u += 0x7fffu + ((u >> 16) & 1u);
    return (unsigned short)(u >> 16);
}
__device__ __forceinline__ unsigned short f2h(float x) {
    union { _Float16 h; unsigned short s; } u;
    u.h = (_Float16)x;
    return u.s;
}
__device__ __forceinline__ f16x8 asf16(bf16x8 v) {
    union { bf16x8 b; f16x8 h; } u; u.b = v; return u.h;
}
__device__ __forceinline__ unsigned packsplit(float x) {
    unsigned hi = f2bf(x);
    float hif = __uint_as_float(hi << 16);
    unsigned lo = f2bf(x - hif);
    return (hi << 16) | lo;
}
__device__ __forceinline__ float unpacksplit(unsigned p) {
    return __uint_as_float(p & 0xffff0000u) + __uint_as_float(p << 16);
}
__device__ __forceinline__ float fsig(float x) { return 1.0f / (1.0f + __expf(-x)); }
__device__ __forceinline__ float ftanh(float x) {
    float cx = fminf(fmaxf(x, -30.0f), 30.0f);
    float t = __expf(2.0f * cx);
    return (t - 1.0f) / (t + 1.0f);
}

__device__ __forceinline__ void unpack8(uint4 a, uint4 b, bf16x8& hi, bf16x8& lo) {
    union U { unsigned u[4]; bf16x8 v; } uh, ul;
    uh.u[0] = (a.x >> 16) | (a.y & 0xffff0000u);
    uh.u[1] = (a.z >> 16) | (a.w & 0xffff0000u);
    uh.u[2] = (b.x >> 16) | (b.y & 0xffff0000u);
    uh.u[3] = (b.z >> 16) | (b.w & 0xffff0000u);
    ul.u[0] = (a.x & 0xffffu) | (a.y << 16);
    ul.u[1] = (a.z & 0xffffu) | (a.w << 16);
    ul.u[2] = (b.x & 0xffffu) | (b.y << 16);
    ul.u[3] = (b.z & 0xffffu) | (b.w << 16);
    hi = uh.v; lo = ul.v;
}

// fp32 -> split bf16 hi/lo pack (initial embedding)
__global__ __launch_bounds__(256) void pack_kernel(
    const float* __restrict__ src, unsigned* __restrict__ dst)
{
    const int i = blockIdx.x * 256 + threadIdx.x;
    const float4 v = ((const float4*)src)[i];
    uint4 o = { packsplit(v.x), packsplit(v.y), packsplit(v.z), packsplit(v.w) };
    ((uint4*)dst)[i] = o;
}

// msg weights -> fragment-major
__global__ __launch_bounds__(256) void wtrans_msg(
    const float* __restrict__ W_msg, __bf16* __restrict__ Wmt)
{
    const int f = blockIdx.x * 256 + threadIdx.x;  // 0..32767
    const int ln = f & 63;
    const int t = (f >> 6) & 7;
    const int c16 = (f >> 9) & 15;
    const int e = f >> 13;
    const int col = c16 * 16 + (ln & 15);
    const int k = t * 32 + (ln >> 4) * 8;
    const float* src = W_msg + ((size_t)e * H + col) * H + k;
    const float4 a = *(const float4*)src;
    const float4 b = *(const float4*)(src + 4);
    ushort4 o0 = { f2bf(a.x), f2bf(a.y), f2bf(a.z), f2bf(a.w) };
    ushort4 o1 = { f2bf(b.x), f2bf(b.y), f2bf(b.z), f2bf(b.w) };
    *(ushort4*)(Wmt + (size_t)f * 8) = o0;
    *(ushort4*)(Wmt + (size_t)f * 8 + 4) = o1;
}

// gate weights -> fragment-major. g 0..2: W_ih r,z,n stored as FP16 bits
// (pairs with fp16 x in gruk's single-MFMA ih path). g 3..5: W_hh r,z,n
// as bf16 (pairs with split-bf16 h).
__global__ __launch_bounds__(256) void wtrans_gate(
    const float* __restrict__ W_ih, const float* __restrict__ W_hh,
    __bf16* __restrict__ Wt)
{
    const int f = blockIdx.x * 256 + threadIdx.x;  // 0..49151
    const int ln = f & 63;
    const int t = (f >> 6) & 7;
    const int c16 = (f >> 9) & 15;
    const int g = f >> 13;
    const int col = c16 * 16 + (ln & 15);
    const int k = t * 32 + (ln >> 4) * 8;
    const float* src = (g < 3) ? (W_ih + ((size_t)g * H + col) * H + k)
                               : (W_hh + ((size_t)(g - 3) * H + col) * H + k);
    const float4 a = *(const float4*)src;
    const float4 b = *(const float4*)(src + 4);
    ushort4 o0, o1;
    if (g < 3) {
        o0 = (ushort4){ f2h(a.x), f2h(a.y), f2h(a.z), f2h(a.w) };
        o1 = (ushort4){ f2h(b.x), f2h(b.y), f2h(b.z), f2h(b.w) };
    } else {
        o0 = (ushort4){ f2bf(a.x), f2bf(a.y), f2bf(a.z), f2bf(a.w) };
        o1 = (ushort4){ f2bf(b.x), f2bf(b.y), f2bf(b.z), f2bf(b.w) };
    }
    *(ushort4*)(Wt + (size_t)f * 8) = o0;
    *(ushort4*)(Wt + (size_t)f * 8 + 4) = o1;
}

// ---- combined CSR build: one list per (b, node), all 4 edge-types ----
__global__ __launch_bounds__(256) void countk2(
    const int* __restrict__ ed0, const int* __restrict__ ed1,
    const int* __restrict__ ed2, const int* __restrict__ ed3,
    int* __restrict__ csrn)
{
    const int i = blockIdx.x * 256 + threadIdx.x;  // 0..B*ET*E-1
    const int edge = i & (E - 1);
    const int be = i >> 13;
    const int b = be >> 2, e = be & 3;
    const int* ed = (e == 0) ? ed0 : (e == 1) ? ed1 : (e == 2) ? ed2 : ed3;
    const int tgt = ed[((size_t)b * E + edge) * 2 + 1];
    atomicAdd(&csrn[(size_t)b * N + tgt], 1);
}

__global__ __launch_bounds__(256) void scank(int* __restrict__ csr)
{
    int* d = csr + (size_t)blockIdx.x * N;
    const int t = threadIdx.x;
    __shared__ int part[256];
    int loc[32];
    const int base = t * 32;
    int s = 0;
    #pragma unroll
    for (int i = 0; i < 32; ++i) { loc[i] = d[base + i]; s += loc[i]; }
    part[t] = s;
    __syncthreads();
    if (t == 0) { int a = 0; for (int i = 0; i < 256; ++i) { int v = part[i]; part[i] = a; a += v; } }
    __syncthreads();
    int a = part[t];
    #pragma unroll
    for (int i = 0; i < 32; ++i) { d[base + i] = a; a += loc[i]; }
}

__global__ __launch_bounds__(256) void fillk2(
    const int* __restrict__ ed0, const int* __restrict__ ed1,
    const int* __restrict__ ed2, const int* __restrict__ ed3,
    int* __restrict__ csrn, int* __restrict__ eslot)
{
    const int i = blockIdx.x * 256 + threadIdx.x;
    const int edge = i & (E - 1);
    const int be = i >> 13;
    const int b = be >> 2, e = be & 3;
    const int* ed = (e == 0) ? ed0 : (e == 1) ? ed1 : (e == 2) ? ed2 : ed3;
    const int tgt = ed[((size_t)b * E + edge) * 2 + 1];
    const int pos = atomicAdd(&csrn[(size_t)b * N + tgt], 1);
    eslot[i] = pos;
}

// msg GEMM v3b (verified R5/R7/R9/R10/R11): 32-row x 256-col blocks, 512 thr
// (8 waves; wave = 32r x 32c, acc 16 AGPR). Single LDS array, hi/lo +0/+8192.
// medge stored as bf16 (R12's fp16 medge caused scratch spills in gruk).
__global__ __launch_bounds__(512, 4) void msgk3(
    const unsigned* __restrict__ hp,
    const int* __restrict__ ed0, const int* __restrict__ ed1,
    const int* __restrict__ ed2, const int* __restrict__ ed3,
    const int* __restrict__ eslot,
    const __bf16* __restrict__ Wmt, const float* __restrict__ b_msg,
    unsigned short* __restrict__ medge, const int b0)
{
    __shared__ __bf16 sS[2 * 32 * 256];  // hi plane, lo plane at +8192
    __shared__ int s_slot[32];
    const int tid = threadIdx.x;
    const int by = blockIdx.y;           // 0..CB*ET-1
    const int bl = by >> 2, e = by & 3;
    const int b = b0 + bl;
    const int* ed = (e == 0) ? ed0 : (e == 1) ? ed1 : (e == 2) ? ed2 : ed3;
    const int row0 = blockIdx.x * 32;

    const int wv = tid >> 6, ln = tid & 63, lq = ln >> 4, lm = ln & 15;
    const int c16a = wv * 2;             // wave cols [wv*32, wv*32+32)

    // early weight preload for ks=0 (L2 latency overlaps the h gather)
    const __bf16* wb = Wmt + (size_t)ln * 8;
    bf16x8 Wc[2], Wn[2];
    #pragma unroll
    for (int nt = 0; nt < 2; ++nt)
        Wc[nt] = *(const bf16x8*)(wb + (size_t)((e * 16 + c16a + nt) * 8) * 512);

    if (tid < 32) s_slot[tid] = eslot[(size_t)(b * ET + e) * E + row0 + tid];

    // ---- staging: thread -> row tid>>4, k-chunks {seg, seg+16} ----
    {
        const int r = tid >> 4;
        const int seg = tid & 15;
        const int src = ed[((size_t)b * E + row0 + r) * 2];
        const unsigned* hrow = hp + ((size_t)b * N + src) * H;
        #pragma unroll
        for (int cc = 0; cc < 2; ++cc) {
            const int c = seg + cc * 16;   // k-chunk index (k = c*8)
            uint4 ha = *(const uint4*)(hrow + c * 8);
            uint4 hb = *(const uint4*)(hrow + c * 8 + 4);
            bf16x8 hi, lo; unpack8(ha, hb, hi, lo);
            const int sc = c ^ (r & 7);
            *(bf16x8*)(sS + r * 256 + sc * 8) = hi;
            *(bf16x8*)(sS + 8192 + r * 256 + sc * 8) = lo;
        }
    }
    __syncthreads();

    f32x4 zero = {0.f, 0.f, 0.f, 0.f};
    f32x4 acc[2][2];  // [nt][mt]
    #pragma unroll
    for (int nt = 0; nt < 2; ++nt) { acc[nt][0] = zero; acc[nt][1] = zero; }

    #pragma unroll
    for (int ks = 0; ks < 8; ++ks) {
        if (ks < 7) {
            #pragma unroll
            for (int nt = 0; nt < 2; ++nt)
                Wn[nt] = *(const bf16x8*)(wb + (size_t)((e * 16 + c16a + nt) * 8 + ks + 1) * 512);
        }
        #pragma unroll
        for (int mt = 0; mt < 2; ++mt) {
            const int rr = mt * 16 + lm;
            const int sc = (ks * 4 + lq) ^ (rr & 7);
            const __bf16* ab = sS + rr * 256 + sc * 8;
            const bf16x8 ahi = *(const bf16x8*)(ab);
            const bf16x8 alo = *(const bf16x8*)(ab + 8192);
            #pragma unroll
            for (int nt = 0; nt < 2; ++nt) {
                acc[nt][mt] = __builtin_amdgcn_mfma_f32_16x16x32_bf16(ahi, Wc[nt], acc[nt][mt], 0, 0, 0);
                acc[nt][mt] = __builtin_amdgcn_mfma_f32_16x16x32_bf16(alo, Wc[nt], acc[nt][mt], 0, 0, 0);
            }
        }
        #pragma unroll
        for (int nt = 0; nt < 2; ++nt) Wc[nt] = Wn[nt];
    }

    unsigned short* mb = medge + (size_t)bl * (ET * E) * H;
    #pragma unroll
    for (int nt = 0; nt < 2; ++nt) {
        const int col = (c16a + nt) * 16 + lm;
        const float bias = b_msg[e * H + col];
        #pragma unroll
        for (int mt = 0; mt < 2; ++mt)
            #pragma unroll
            for (int rr = 0; rr < 4; ++rr) {
                const int slot = s_slot[mt * 16 + lq * 4 + rr];
                mb[(size_t)slot * H + col] = f2bf(acc[nt][mt][rr] + bias);
            }
    }
}

// Fused GRU v14: exact R11-verified body (fp16 x-plane, bf16 medge gather,
// hold prefetch, hp ping-pong) with ONE change: __launch_bounds__(512, 6)
// -> 3 blocks/CU (3 x 48KB LDS = 144 <= 160KB; 24 waves <= 32; VGPR 112/wave
// fits). The R11 LDS shrink (64->48KB) unlocked the third resident block;
// its gather/staging latency now hides under the other two blocks' K-loops
// (same mechanism as the R3 2-block win, one notch further).
__global__ __launch_bounds__(512, 6) void gruk(
    const unsigned short* __restrict__ medge, const int* __restrict__ csrn,
    const unsigned* __restrict__ hin, unsigned* __restrict__ hout,
    const __bf16* __restrict__ Wt,
    const float* __restrict__ b_ih, const float* __restrict__ b_hh,
    const int b0)
{
    __shared__ __bf16 sA[3 * 32 * 256];  // 49152 B; planes: x16 / hhi / hlo

    const int tid = threadIdx.x;
    const int g = blockIdx.x;
    const int R = gridDim.x >> 1;                      // rowblks this dispatch
    const int s = g >> 3;
    const int rowblk = (g & 7) * (R >> 3) + (s >> 1);  // 0..R-1
    const int ch = s & 1;                              // col half: [ch*128, +128)
    const int lrow0 = rowblk * 32;                     // chunk-local row base
    const size_t grow0 = (size_t)b0 * N + lrow0;       // global row base

    const int wv = tid >> 6, ln = tid & 63, lq = ln >> 4, lm = ln & 15;
    const int c16 = ch * 8 + wv;                       // wave's single c16 tile
    const int col = c16 * 16 + lm;

    // ---- staging with fused CSR gather: thread -> row tid>>4, 16 k @ (tid&15)*16
    {
        const int r = tid >> 4;
        const int k0 = (tid & 15) * 16;
        const int local = lrow0 + r;
        const int bl = local >> 13;                    // batch within chunk
        const int nn = local & (N - 1);
        const int bb = b0 + bl;
        const int end = csrn[(size_t)bb * N + nn];
        const int start = nn ? csrn[(size_t)bb * N + nn - 1] : 0;

        // independent h-row loads issued BEFORE the gather loop: their
        // ~L2/L3 latency hides under the CSR gather's scattered reads.
        const unsigned* hr = hin + (grow0 + r) * H + k0;
        const uint4 h0 = ((const uint4*)hr)[0];
        const uint4 h1 = ((const uint4*)hr)[1];
        const uint4 h2 = ((const uint4*)hr)[2];
        const uint4 h3 = ((const uint4*)hr)[3];

        float xs[16];
        #pragma unroll
        for (int j = 0; j < 16; ++j) xs[j] = 0.f;

        const unsigned* mbase = (const unsigned*)medge
            + (size_t)bl * (ET * E) * (H / 2) + (k0 >> 1);

        int i = start;
        // 4-edge batches: 8 x 16B loads issued before any accumulation.
        for (; i + 4 <= end; i += 4) {
            uint4 q[8];
            #pragma unroll
            for (int ee = 0; ee < 4; ++ee) {
                const uint4* mr = (const uint4*)(mbase + (size_t)(i + ee) * (H / 2));
                q[ee * 2 + 0] = mr[0];
                q[ee * 2 + 1] = mr[1];
            }
            #pragma unroll
            for (int qi = 0; qi < 8; ++qi) {
                const int eb = (qi & 1) * 8;
                const unsigned pw[4] = { q[qi].x, q[qi].y, q[qi].z, q[qi].w };
                #pragma unroll
                for (int j = 0; j < 4; ++j) {
                    xs[eb + 2 * j]     += __uint_as_float(pw[j] << 16);
                    xs[eb + 2 * j + 1] += __uint_as_float(pw[j] & 0xffff0000u);
                }
            }
        }
        for (; i < end; ++i) {
            const uint4* mr = (const uint4*)(mbase + (size_t)i * (H / 2));
            uint4 q[2];
            q[0] = mr[0]; q[1] = mr[1];
            #pragma unroll
            for (int qi = 0; qi < 2; ++qi) {
                const int eb = qi * 8;
                const unsigned pw[4] = { q[qi].x, q[qi].y, q[qi].z, q[qi].w };
                #pragma unroll
                for (int j = 0; j < 4; ++j) {
                    xs[eb + 2 * j]     += __uint_as_float(pw[j] << 16);
                    xs[eb + 2 * j + 1] += __uint_as_float(pw[j] & 0xffff0000u);
                }
            }
        }

        #pragma unroll
        for (int cc = 0; cc < 2; ++cc) {
            const uint4 ha = cc ? h2 : h0;
            const uint4 hb = cc ? h3 : h1;
            bf16x8 hhi, hlo;
            unpack8(ha, hb, hhi, hlo);
            union Ux { unsigned short us[8]; bf16x8 v; } xf;
            #pragma unroll
            for (int j = 0; j < 8; ++j)
                xf.us[j] = f2h(xs[cc * 8 + j]);
            const int sc = ((k0 >> 3) + cc) ^ (r & 7);
            __bf16* base = sA + r * 256 + sc * 8;
            *(bf16x8*)(base)          = xf.v;   // x plane (fp16 bits)
            *(bf16x8*)(base + 8192)   = hhi;
            *(bf16x8*)(base + 16384)  = hlo;
        }
    }

    // ---- weight preload for ks=0 (issues before barrier) ----
    const __bf16* wb = Wt + (size_t)ln * 8;
    bf16x8 Wc[6], Wn[6];
    #pragma unroll
    for (int g2 = 0; g2 < 6; ++g2)
        Wc[g2] = *(const bf16x8*)(wb + (size_t)((g2 * 16 + c16) * 8) * 512);

    // ---- hold prefetch: the 8 h_t words this lane's epilogue needs,
    // loaded as packed-split u32 from hin (L2-warm); latency hides under
    // the K-loop. Safe vs other blocks: all writes go to hout.
    unsigned holdw[8];
    #pragma unroll
    for (int mt = 0; mt < 2; ++mt)
        #pragma unroll
        for (int rr = 0; rr < 4; ++rr)
            holdw[mt * 4 + rr] = hin[(grow0 + mt * 16 + lq * 4 + rr) * H + col];

    __syncthreads();

    f32x4 zero = {0.f, 0.f, 0.f, 0.f};
    f32x4 acc[6][2];  // [g][mt]
    #pragma unroll
    for (int g2 = 0; g2 < 6; ++g2) { acc[g2][0] = zero; acc[g2][1] = zero; }

    #pragma unroll
    for (int ks = 0; ks < 8; ++ks) {
        if (ks < 7) {
            #pragma unroll
            for (int g2 = 0; g2 < 6; ++g2)
                Wn[g2] = *(const bf16x8*)(wb + (size_t)((g2 * 16 + c16) * 8 + ks + 1) * 512);
        }
        #pragma unroll
        for (int mt = 0; mt < 2; ++mt) {
            const int rr = mt * 16 + lm;
            const int sc = (ks * 4 + lq) ^ (rr & 7);
            const __bf16* ab = sA + rr * 256 + sc * 8;
            const bf16x8 xf  = *(const bf16x8*)(ab);
            const bf16x8 hhi = *(const bf16x8*)(ab + 8192);
            const bf16x8 hlo = *(const bf16x8*)(ab + 16384);
            #pragma unroll
            for (int g2 = 0; g2 < 3; ++g2)
                acc[g2][mt] = __builtin_amdgcn_mfma_f32_16x16x32_f16(
                    asf16(xf), asf16(Wc[g2]), acc[g2][mt], 0, 0, 0);
            #pragma unroll
            for (int g2 = 3; g2 < 6; ++g2) {
                acc[g2][mt] = __builtin_amdgcn_mfma_f32_16x16x32_bf16(hhi, Wc[g2], acc[g2][mt], 0, 0, 0);
                acc[g2][mt] = __builtin_amdgcn_mfma_f32_16x16x32_bf16(hlo, Wc[g2], acc[g2][mt], 0, 0, 0);
            }
        }
        #pragma unroll
        for (int g2 = 0; g2 < 6; ++g2) Wc[g2] = Wn[g2];
    }

    // ---- fused gates; hold from prefetched registers; store to hout ----
    {
        const float bi_r = b_ih[col], bi_z = b_ih[H + col], bi_n = b_ih[2 * H + col];
        const float bh_r = b_hh[col], bh_z = b_hh[H + col], bh_n = b_hh[2 * H + col];
        #pragma unroll
        for (int mt = 0; mt < 2; ++mt) {
            #pragma unroll
            for (int rr = 0; rr < 4; ++rr) {
                const int lrow = mt * 16 + lq * 4 + rr;  // block-local row
                const float hold = unpacksplit(holdw[mt * 4 + rr]);
                const float rg = fsig(acc[0][mt][rr] + bi_r + acc[3][mt][rr] + bh_r);
                const float zg = fsig(acc[1][mt][rr] + bi_z + acc[4][mt][rr] + bh_z);
                const float ng = ftanh(acc[2][mt][rr] + bi_n + rg * (acc[5][mt][rr] + bh_n));
                const float o = (1.0f - zg) * ng + zg * hold;
                hout[(grow0 + lrow) * H + col] = packsplit(o);
            }
        }
    }
}

__global__ __launch_bounds__(256) void sel_kernel(
    const unsigned* __restrict__ hpack, const int* __restrict__ nao,
    float* __restrict__ out)
{
    const int row = blockIdx.x * 4 + (threadIdx.x >> 6);
    const int lane = threadIdx.x & 63;
    const int b = row >> 11;  // M = 2048
    const int idx = nao[row];
    const uint4 p = ((const uint4*)(hpack + ((size_t)b * N + idx) * H))[lane];
    float4 v = { unpacksplit(p.x), unpacksplit(p.y), unpacksplit(p.z), unpacksplit(p.w) };
    ((float4*)(out + (size_t)row * H))[lane] = v;
}

__global__ __launch_bounds__(256) void gmean_kernel(
    const float* __restrict__ sel, float* __restrict__ gacc)
{
    const int b = blockIdx.x >> 4;
    const int c = blockIdx.x & 15;
    const int j = threadIdx.x;
    float s = 0.0f;
    const float* base = sel + ((size_t)b * M + (size_t)c * 128) * H + j;
    for (int m = 0; m < 128; ++m) s += base[(size_t)m * H];
    atomicAdd(&gacc[b * H + j], s);
}

__global__ __launch_bounds__(256) void final_kernel(
    const float* __restrict__ gacc, float* __restrict__ out)
{
    const int i = blockIdx.x * 256 + threadIdx.x;
    const size_t sel_sz = (size_t)B * M * H;
    if (i < B * M) {
        out[sel_sz + i] = 1.0f;
    } else {
        const int j = i - B * M;
        out[sel_sz + B * M + j] = tanhf(gacc[j] * (1.0f / (float)M));
    }
}

extern "C" void kernel_launch(void* const* d_in, const int* in_sizes, int n_in,
                              void* d_out, int out_size, void* d_ws, size_t ws_size,
                              hipStream_t stream) {
    const float* emb  = (const float*)d_in[0];
    const int*   nao  = (const int*)d_in[2];
    const int*   ed0  = (const int*)d_in[3];
    const int*   ed1  = (const int*)d_in[4];
    const int*   ed2  = (const int*)d_in[5];
    const int*   ed3  = (const int*)d_in[6];
    const float* W_msg = (const float*)d_in[7];
    const float* b_msg = (const float*)d_in[8];
    const float* W_ih  = (const float*)d_in[9];
    const float* W_hh  = (const float*)d_in[10];
    const float* b_ih  = (const float*)d_in[11];
    const float* b_hh  = (const float*)d_in[12];
    float* out = (float*)d_out;

    const size_t helems = (size_t)B * N * H;       // 8.39M

    // hp ping-pong (2 x 33.55 MB) + medge chunks. CB=4 needs ~137 MB,
    // CB=2 needs ~103 MB.
    const size_t fixed_tail = ((size_t)ET * 16 * 8 * 64 * 8) * 2   // Wmt
                            + ((size_t)6 * 16 * 8 * 64 * 8) * 2    // Wt
                            + (size_t)B * N * 4                    // csrn
                            + (size_t)B * ET * E * 4               // eslot
                            + (size_t)B * H * 4;                   // gacc
    const size_t need4 = helems * 8 + (size_t)4 * ET * E * H * 2 + fixed_tail;
    const int CB = (ws_size >= need4) ? 4 : 2;

    unsigned*       hp0   = (unsigned*)d_ws;                              // 33.55 MB
    unsigned*       hp1   = hp0 + helems;                                 // 33.55 MB
    unsigned short* medge = (unsigned short*)(hp1 + helems);              // CB*16.78 MB
    __bf16*   Wmt   = (__bf16*)(medge + (size_t)CB * ET * E * H);
    __bf16*   Wt    = Wmt + (size_t)ET * 16 * 8 * 64 * 8;
    int*      csrn  = (int*)(Wt + (size_t)6 * 16 * 8 * 64 * 8);
    int*      eslot = csrn + (size_t)B * N;
    float*    gacc  = (float*)(eslot + (size_t)B * ET * E);

    // ---- setup ----
    pack_kernel<<<dim3(helems / 4 / 256), 256, 0, stream>>>(emb, hp0);
    wtrans_msg<<<dim3(128), 256, 0, stream>>>(W_msg, Wmt);
    wtrans_gate<<<dim3(192), 256, 0, stream>>>(W_ih, W_hh, Wt);
    hipMemsetAsync(csrn, 0, (size_t)B * N * sizeof(int), stream);
    countk2<<<dim3(B * ET * E / 256), 256, 0, stream>>>(ed0, ed1, ed2, ed3, csrn);
    scank<<<dim3(B), 256, 0, stream>>>(csrn);
    fillk2<<<dim3(B * ET * E / 256), 256, 0, stream>>>(ed0, ed1, ed2, ed3, csrn, eslot);

    // ---- T iterations, CB-batch chunks, hp ping-pong ----
    // t even: hin=hp0, hout=hp1; t odd: hin=hp1, hout=hp0.
    // T_ITERS=8 -> final h lands in hp0.
    for (int t = 0; t < T_ITERS; ++t) {
        const unsigned* hin  = (t & 1) ? hp1 : hp0;
        unsigned*       hout = (t & 1) ? hp0 : hp1;
        for (int bc = 0; bc < B / CB; ++bc) {
            msgk3<<<dim3(E / 32, CB * ET), 512, 0, stream>>>(
                hin, ed0, ed1, ed2, ed3, eslot, Wmt, b_msg, medge, bc * CB);
            gruk<<<dim3(CB * N / 32 * 2), 512, 0, stream>>>(
                medge, csrn, hin, hout, Wt, b_ih, b_hh, bc * CB);
        }
    }

    // ---- epilogue (final h in hp0) ----
    hipMemsetAsync(gacc, 0, (size_t)B * H * sizeof(float), stream);
    sel_kernel<<<dim3(B * M / 4), 256, 0, stream>>>(hp0, nao, out);
    gmean_kernel<<<dim3(B * 16), 256, 0, stream>>>(out, gacc);
    final_kernel<<<dim3((B * M + B * H) / 256), 256, 0, stream>>>(gacc, out);
}

// Round 14
// 1029.811 us; speedup vs baseline: 2.0294x; 2.0294x over previous
//
#include <hip/hip_runtime.h>

#define B 4
#define N 8192
#define H 256
#define E 8192
#define M 2048
#define T_ITERS 8
#define ET 4

typedef __bf16 bf16x8 __attribute__((ext_vector_type(8)));
typedef _Float16 f16x8 __attribute__((ext_vector_type(8)));
typedef float f32x4 __attribute__((ext_vector_type(4)));

__device__ __forceinline__ unsigned short f2bf(float x) {
    unsigned u = __float_as_uint(x);
    u += 0x7fffu + ((u >> 16) & 1u);
    return (unsigned short)(u >> 16);
}
__device__ __forceinline__ unsigned short f2h(float x) {
    union { _Float16 h; unsigned short s; } u;
    u.h = (_Float16)x;
    return u.s;
}
__device__ __forceinline__ f16x8 asf16(bf16x8 v) {
    union { bf16x8 b; f16x8 h; } u; u.b = v; return u.h;
}
__device__ __forceinline__ unsigned packsplit(float x) {
    unsigned hi = f2bf(x);
    float hif = __uint_as_float(hi << 16);
    unsigned lo = f2bf(x - hif);
    return (hi << 16) | lo;
}
__device__ __forceinline__ float unpacksplit(unsigned p) {
    return __uint_as_float(p & 0xffff0000u) + __uint_as_float(p << 16);
}
__device__ __forceinline__ float fsig(float x) { return 1.0f / (1.0f + __expf(-x)); }
__device__ __forceinline__ float ftanh(float x) {
    float cx = fminf(fmaxf(x, -30.0f), 30.0f);
    float t = __expf(2.0f * cx);
    return (t - 1.0f) / (t + 1.0f);
}

__device__ __forceinline__ void unpack8(uint4 a, uint4 b, bf16x8& hi, bf16x8& lo) {
    union U { unsigned u[4]; bf16x8 v; } uh, ul;
    uh.u[0] = (a.x >> 16) | (a.y & 0xffff0000u);
    uh.u[1] = (a.z >> 16) | (a.w & 0xffff0000u);
    uh.u[2] = (b.x >> 16) | (b.y & 0xffff0000u);
    uh.u[3] = (b.z >> 16) | (b.w & 0xffff0000u);
    ul.u[0] = (a.x & 0xffffu) | (a.y << 16);
    ul.u[1] = (a.z & 0xffffu) | (a.w << 16);
    ul.u[2] = (b.x & 0xffffu) | (b.y << 16);
    ul.u[3] = (b.z & 0xffffu) | (b.w << 16);
    hi = uh.v; lo = ul.v;
}

// fp32 -> split bf16 hi/lo pack (initial embedding)
__global__ __launch_bounds__(256) void pack_kernel(
    const float* __restrict__ src, unsigned* __restrict__ dst)
{
    const int i = blockIdx.x * 256 + threadIdx.x;
    const float4 v = ((const float4*)src)[i];
    uint4 o = { packsplit(v.x), packsplit(v.y), packsplit(v.z), packsplit(v.w) };
    ((uint4*)dst)[i] = o;
}

// msg weights -> fragment-major
__global__ __launch_bounds__(256) void wtrans_msg(
    const float* __restrict__ W_msg, __bf16* __restrict__ Wmt)
{
    const int f = blockIdx.x * 256 + threadIdx.x;  // 0..32767
    const int ln = f & 63;
    const int t = (f >> 6) & 7;
    const int c16 = (f >> 9) & 15;
    const int e = f >> 13;
    const int col = c16 * 16 + (ln & 15);
    const int k = t * 32 + (ln >> 4) * 8;
    const float* src = W_msg + ((size_t)e * H + col) * H + k;
    const float4 a = *(const float4*)src;
    const float4 b = *(const float4*)(src + 4);
    ushort4 o0 = { f2bf(a.x), f2bf(a.y), f2bf(a.z), f2bf(a.w) };
    ushort4 o1 = { f2bf(b.x), f2bf(b.y), f2bf(b.z), f2bf(b.w) };
    *(ushort4*)(Wmt + (size_t)f * 8) = o0;
    *(ushort4*)(Wmt + (size_t)f * 8 + 4) = o1;
}

// gate weights -> fragment-major. g 0..2: W_ih r,z,n stored as FP16 bits
// (pairs with fp16 x in gruk's single-MFMA ih path). g 3..5: W_hh r,z,n
// as bf16 (pairs with split-bf16 h).
__global__ __launch_bounds__(256) void wtrans_gate(
    const float* __restrict__ W_ih, const float* __restrict__ W_hh,
    __bf16* __restrict__ Wt)
{
    const int f = blockIdx.x * 256 + threadIdx.x;  // 0..49151
    const int ln = f & 63;
    const int t = (f >> 6) & 7;
    const int c16 = (f >> 9) & 15;
    const int g = f >> 13;
    const int col = c16 * 16 + (ln & 15);
    const int k = t * 32 + (ln >> 4) * 8;
    const float* src = (g < 3) ? (W_ih + ((size_t)g * H + col) * H + k)
                               : (W_hh + ((size_t)(g - 3) * H + col) * H + k);
    const float4 a = *(const float4*)src;
    const float4 b = *(const float4*)(src + 4);
    ushort4 o0, o1;
    if (g < 3) {
        o0 = (ushort4){ f2h(a.x), f2h(a.y), f2h(a.z), f2h(a.w) };
        o1 = (ushort4){ f2h(b.x), f2h(b.y), f2h(b.z), f2h(b.w) };
    } else {
        o0 = (ushort4){ f2bf(a.x), f2bf(a.y), f2bf(a.z), f2bf(a.w) };
        o1 = (ushort4){ f2bf(b.x), f2bf(b.y), f2bf(b.z), f2bf(b.w) };
    }
    *(ushort4*)(Wt + (size_t)f * 8) = o0;
    *(ushort4*)(Wt + (size_t)f * 8 + 4) = o1;
}

// ---- combined CSR build: one list per (b, node), all 4 edge-types ----
__global__ __launch_bounds__(256) void countk2(
    const int* __restrict__ ed0, const int* __restrict__ ed1,
    const int* __restrict__ ed2, const int* __restrict__ ed3,
    int* __restrict__ csrn)
{
    const int i = blockIdx.x * 256 + threadIdx.x;  // 0..B*ET*E-1
    const int edge = i & (E - 1);
    const int be = i >> 13;
    const int b = be >> 2, e = be & 3;
    const int* ed = (e == 0) ? ed0 : (e == 1) ? ed1 : (e == 2) ? ed2 : ed3;
    const int tgt = ed[((size_t)b * E + edge) * 2 + 1];
    atomicAdd(&csrn[(size_t)b * N + tgt], 1);
}

__global__ __launch_bounds__(256) void scank(int* __restrict__ csr)
{
    int* d = csr + (size_t)blockIdx.x * N;
    const int t = threadIdx.x;
    __shared__ int part[256];
    int loc[32];
    const int base = t * 32;
    int s = 0;
    #pragma unroll
    for (int i = 0; i < 32; ++i) { loc[i] = d[base + i]; s += loc[i]; }
    part[t] = s;
    __syncthreads();
    if (t == 0) { int a = 0; for (int i = 0; i < 256; ++i) { int v = part[i]; part[i] = a; a += v; } }
    __syncthreads();
    int a = part[t];
    #pragma unroll
    for (int i = 0; i < 32; ++i) { d[base + i] = a; a += loc[i]; }
}

__global__ __launch_bounds__(256) void fillk2(
    const int* __restrict__ ed0, const int* __restrict__ ed1,
    const int* __restrict__ ed2, const int* __restrict__ ed3,
    int* __restrict__ csrn, int* __restrict__ eslot)
{
    const int i = blockIdx.x * 256 + threadIdx.x;
    const int edge = i & (E - 1);
    const int be = i >> 13;
    const int b = be >> 2, e = be & 3;
    const int* ed = (e == 0) ? ed0 : (e == 1) ? ed1 : (e == 2) ? ed2 : ed3;
    const int tgt = ed[((size_t)b * E + edge) * 2 + 1];
    const int pos = atomicAdd(&csrn[(size_t)b * N + tgt], 1);
    eslot[i] = pos;
}

// msg GEMM v3b (verified R5/R7/R9/R10/R11): 32-row x 256-col blocks, 512 thr
// (8 waves; wave = 32r x 32c, acc 16 AGPR). Single LDS array, hi/lo +0/+8192.
// medge stored as bf16 (R12's fp16 medge caused scratch spills in gruk).
__global__ __launch_bounds__(512, 4) void msgk3(
    const unsigned* __restrict__ hp,
    const int* __restrict__ ed0, const int* __restrict__ ed1,
    const int* __restrict__ ed2, const int* __restrict__ ed3,
    const int* __restrict__ eslot,
    const __bf16* __restrict__ Wmt, const float* __restrict__ b_msg,
    unsigned short* __restrict__ medge, const int b0)
{
    __shared__ __bf16 sS[2 * 32 * 256];  // hi plane, lo plane at +8192
    __shared__ int s_slot[32];
    const int tid = threadIdx.x;
    const int by = blockIdx.y;           // 0..CB*ET-1
    const int bl = by >> 2, e = by & 3;
    const int b = b0 + bl;
    const int* ed = (e == 0) ? ed0 : (e == 1) ? ed1 : (e == 2) ? ed2 : ed3;
    const int row0 = blockIdx.x * 32;

    const int wv = tid >> 6, ln = tid & 63, lq = ln >> 4, lm = ln & 15;
    const int c16a = wv * 2;             // wave cols [wv*32, wv*32+32)

    // early weight preload for ks=0 (L2 latency overlaps the h gather)
    const __bf16* wb = Wmt + (size_t)ln * 8;
    bf16x8 Wc[2], Wn[2];
    #pragma unroll
    for (int nt = 0; nt < 2; ++nt)
        Wc[nt] = *(const bf16x8*)(wb + (size_t)((e * 16 + c16a + nt) * 8) * 512);

    if (tid < 32) s_slot[tid] = eslot[(size_t)(b * ET + e) * E + row0 + tid];

    // ---- staging: thread -> row tid>>4, k-chunks {seg, seg+16} ----
    {
        const int r = tid >> 4;
        const int seg = tid & 15;
        const int src = ed[((size_t)b * E + row0 + r) * 2];
        const unsigned* hrow = hp + ((size_t)b * N + src) * H;
        #pragma unroll
        for (int cc = 0; cc < 2; ++cc) {
            const int c = seg + cc * 16;   // k-chunk index (k = c*8)
            uint4 ha = *(const uint4*)(hrow + c * 8);
            uint4 hb = *(const uint4*)(hrow + c * 8 + 4);
            bf16x8 hi, lo; unpack8(ha, hb, hi, lo);
            const int sc = c ^ (r & 7);
            *(bf16x8*)(sS + r * 256 + sc * 8) = hi;
            *(bf16x8*)(sS + 8192 + r * 256 + sc * 8) = lo;
        }
    }
    __syncthreads();

    f32x4 zero = {0.f, 0.f, 0.f, 0.f};
    f32x4 acc[2][2];  // [nt][mt]
    #pragma unroll
    for (int nt = 0; nt < 2; ++nt) { acc[nt][0] = zero; acc[nt][1] = zero; }

    #pragma unroll
    for (int ks = 0; ks < 8; ++ks) {
        if (ks < 7) {
            #pragma unroll
            for (int nt = 0; nt < 2; ++nt)
                Wn[nt] = *(const bf16x8*)(wb + (size_t)((e * 16 + c16a + nt) * 8 + ks + 1) * 512);
        }
        #pragma unroll
        for (int mt = 0; mt < 2; ++mt) {
            const int rr = mt * 16 + lm;
            const int sc = (ks * 4 + lq) ^ (rr & 7);
            const __bf16* ab = sS + rr * 256 + sc * 8;
            const bf16x8 ahi = *(const bf16x8*)(ab);
            const bf16x8 alo = *(const bf16x8*)(ab + 8192);
            #pragma unroll
            for (int nt = 0; nt < 2; ++nt) {
                acc[nt][mt] = __builtin_amdgcn_mfma_f32_16x16x32_bf16(ahi, Wc[nt], acc[nt][mt], 0, 0, 0);
                acc[nt][mt] = __builtin_amdgcn_mfma_f32_16x16x32_bf16(alo, Wc[nt], acc[nt][mt], 0, 0, 0);
            }
        }
        #pragma unroll
        for (int nt = 0; nt < 2; ++nt) Wc[nt] = Wn[nt];
    }

    unsigned short* mb = medge + (size_t)bl * (ET * E) * H;
    #pragma unroll
    for (int nt = 0; nt < 2; ++nt) {
        const int col = (c16a + nt) * 16 + lm;
        const float bias = b_msg[e * H + col];
        #pragma unroll
        for (int mt = 0; mt < 2; ++mt)
            #pragma unroll
            for (int rr = 0; rr < 4; ++rr) {
                const int slot = s_slot[mt * 16 + lq * 4 + rr];
                mb[(size_t)slot * H + col] = f2bf(acc[nt][mt][rr] + bias);
            }
    }
}

// Fused GRU v12r (exact R11-verified body, 70.4us): fp16 x-plane single-MFMA
// ih path, bf16 medge gather with fp32 accumulation, hold prefetch, hp
// ping-pong, XCD-pairing remap. __launch_bounds__(512, 4): this kernel's
// working set is ~112 regs/wave (64 arch + 48 acc) -> 4 waves/SIMD is the
// occupancy ceiling; (512,6) forced VGPR=40 + 562MB of spill traffic (R13).
__global__ __launch_bounds__(512, 4) void gruk(
    const unsigned short* __restrict__ medge, const int* __restrict__ csrn,
    const unsigned* __restrict__ hin, unsigned* __restrict__ hout,
    const __bf16* __restrict__ Wt,
    const float* __restrict__ b_ih, const float* __restrict__ b_hh,
    const int b0)
{
    __shared__ __bf16 sA[3 * 32 * 256];  // 49152 B; planes: x16 / hhi / hlo

    const int tid = threadIdx.x;
    const int g = blockIdx.x;
    const int R = gridDim.x >> 1;                      // rowblks this dispatch
    const int s = g >> 3;
    const int rowblk = (g & 7) * (R >> 3) + (s >> 1);  // 0..R-1
    const int ch = s & 1;                              // col half: [ch*128, +128)
    const int lrow0 = rowblk * 32;                     // chunk-local row base
    const size_t grow0 = (size_t)b0 * N + lrow0;       // global row base

    const int wv = tid >> 6, ln = tid & 63, lq = ln >> 4, lm = ln & 15;
    const int c16 = ch * 8 + wv;                       // wave's single c16 tile
    const int col = c16 * 16 + lm;

    // ---- staging with fused CSR gather: thread -> row tid>>4, 16 k @ (tid&15)*16
    {
        const int r = tid >> 4;
        const int k0 = (tid & 15) * 16;
        const int local = lrow0 + r;
        const int bl = local >> 13;                    // batch within chunk
        const int nn = local & (N - 1);
        const int bb = b0 + bl;
        const int end = csrn[(size_t)bb * N + nn];
        const int start = nn ? csrn[(size_t)bb * N + nn - 1] : 0;

        // independent h-row loads issued BEFORE the gather loop: their
        // ~L2/L3 latency hides under the CSR gather's scattered reads.
        const unsigned* hr = hin + (grow0 + r) * H + k0;
        const uint4 h0 = ((const uint4*)hr)[0];
        const uint4 h1 = ((const uint4*)hr)[1];
        const uint4 h2 = ((const uint4*)hr)[2];
        const uint4 h3 = ((const uint4*)hr)[3];

        float xs[16];
        #pragma unroll
        for (int j = 0; j < 16; ++j) xs[j] = 0.f;

        const unsigned* mbase = (const unsigned*)medge
            + (size_t)bl * (ET * E) * (H / 2) + (k0 >> 1);

        int i = start;
        // 4-edge batches: 8 x 16B loads issued before any accumulation.
        for (; i + 4 <= end; i += 4) {
            uint4 q[8];
            #pragma unroll
            for (int ee = 0; ee < 4; ++ee) {
                const uint4* mr = (const uint4*)(mbase + (size_t)(i + ee) * (H / 2));
                q[ee * 2 + 0] = mr[0];
                q[ee * 2 + 1] = mr[1];
            }
            #pragma unroll
            for (int qi = 0; qi < 8; ++qi) {
                const int eb = (qi & 1) * 8;
                const unsigned pw[4] = { q[qi].x, q[qi].y, q[qi].z, q[qi].w };
                #pragma unroll
                for (int j = 0; j < 4; ++j) {
                    xs[eb + 2 * j]     += __uint_as_float(pw[j] << 16);
                    xs[eb + 2 * j + 1] += __uint_as_float(pw[j] & 0xffff0000u);
                }
            }
        }
        for (; i < end; ++i) {
            const uint4* mr = (const uint4*)(mbase + (size_t)i * (H / 2));
            uint4 q[2];
            q[0] = mr[0]; q[1] = mr[1];
            #pragma unroll
            for (int qi = 0; qi < 2; ++qi) {
                const int eb = qi * 8;
                const unsigned pw[4] = { q[qi].x, q[qi].y, q[qi].z, q[qi].w };
                #pragma unroll
                for (int j = 0; j < 4; ++j) {
                    xs[eb + 2 * j]     += __uint_as_float(pw[j] << 16);
                    xs[eb + 2 * j + 1] += __uint_as_float(pw[j] & 0xffff0000u);
                }
            }
        }

        #pragma unroll
        for (int cc = 0; cc < 2; ++cc) {
            const uint4 ha = cc ? h2 : h0;
            const uint4 hb = cc ? h3 : h1;
            bf16x8 hhi, hlo;
            unpack8(ha, hb, hhi, hlo);
            union Ux { unsigned short us[8]; bf16x8 v; } xf;
            #pragma unroll
            for (int j = 0; j < 8; ++j)
                xf.us[j] = f2h(xs[cc * 8 + j]);
            const int sc = ((k0 >> 3) + cc) ^ (r & 7);
            __bf16* base = sA + r * 256 + sc * 8;
            *(bf16x8*)(base)          = xf.v;   // x plane (fp16 bits)
            *(bf16x8*)(base + 8192)   = hhi;
            *(bf16x8*)(base + 16384)  = hlo;
        }
    }

    // ---- weight preload for ks=0 (issues before barrier) ----
    const __bf16* wb = Wt + (size_t)ln * 8;
    bf16x8 Wc[6], Wn[6];
    #pragma unroll
    for (int g2 = 0; g2 < 6; ++g2)
        Wc[g2] = *(const bf16x8*)(wb + (size_t)((g2 * 16 + c16) * 8) * 512);

    // ---- hold prefetch: the 8 h_t words this lane's epilogue needs,
    // loaded as packed-split u32 from hin (L2-warm); latency hides under
    // the K-loop. Safe vs other blocks: all writes go to hout.
    unsigned holdw[8];
    #pragma unroll
    for (int mt = 0; mt < 2; ++mt)
        #pragma unroll
        for (int rr = 0; rr < 4; ++rr)
            holdw[mt * 4 + rr] = hin[(grow0 + mt * 16 + lq * 4 + rr) * H + col];

    __syncthreads();

    f32x4 zero = {0.f, 0.f, 0.f, 0.f};
    f32x4 acc[6][2];  // [g][mt]
    #pragma unroll
    for (int g2 = 0; g2 < 6; ++g2) { acc[g2][0] = zero; acc[g2][1] = zero; }

    #pragma unroll
    for (int ks = 0; ks < 8; ++ks) {
        if (ks < 7) {
            #pragma unroll
            for (int g2 = 0; g2 < 6; ++g2)
                Wn[g2] = *(const bf16x8*)(wb + (size_t)((g2 * 16 + c16) * 8 + ks + 1) * 512);
        }
        #pragma unroll
        for (int mt = 0; mt < 2; ++mt) {
            const int rr = mt * 16 + lm;
            const int sc = (ks * 4 + lq) ^ (rr & 7);
            const __bf16* ab = sA + rr * 256 + sc * 8;
            const bf16x8 xf  = *(const bf16x8*)(ab);
            const bf16x8 hhi = *(const bf16x8*)(ab + 8192);
            const bf16x8 hlo = *(const bf16x8*)(ab + 16384);
            #pragma unroll
            for (int g2 = 0; g2 < 3; ++g2)
                acc[g2][mt] = __builtin_amdgcn_mfma_f32_16x16x32_f16(
                    asf16(xf), asf16(Wc[g2]), acc[g2][mt], 0, 0, 0);
            #pragma unroll
            for (int g2 = 3; g2 < 6; ++g2) {
                acc[g2][mt] = __builtin_amdgcn_mfma_f32_16x16x32_bf16(hhi, Wc[g2], acc[g2][mt], 0, 0, 0);
                acc[g2][mt] = __builtin_amdgcn_mfma_f32_16x16x32_bf16(hlo, Wc[g2], acc[g2][mt], 0, 0, 0);
            }
        }
        #pragma unroll
        for (int g2 = 0; g2 < 6; ++g2) Wc[g2] = Wn[g2];
    }

    // ---- fused gates; hold from prefetched registers; store to hout ----
    {
        const float bi_r = b_ih[col], bi_z = b_ih[H + col], bi_n = b_ih[2 * H + col];
        const float bh_r = b_hh[col], bh_z = b_hh[H + col], bh_n = b_hh[2 * H + col];
        #pragma unroll
        for (int mt = 0; mt < 2; ++mt) {
            #pragma unroll
            for (int rr = 0; rr < 4; ++rr) {
                const int lrow = mt * 16 + lq * 4 + rr;  // block-local row
                const float hold = unpacksplit(holdw[mt * 4 + rr]);
                const float rg = fsig(acc[0][mt][rr] + bi_r + acc[3][mt][rr] + bh_r);
                const float zg = fsig(acc[1][mt][rr] + bi_z + acc[4][mt][rr] + bh_z);
                const float ng = ftanh(acc[2][mt][rr] + bi_n + rg * (acc[5][mt][rr] + bh_n));
                const float o = (1.0f - zg) * ng + zg * hold;
                hout[(grow0 + lrow) * H + col] = packsplit(o);
            }
        }
    }
}

__global__ __launch_bounds__(256) void sel_kernel(
    const unsigned* __restrict__ hpack, const int* __restrict__ nao,
    float* __restrict__ out)
{
    const int row = blockIdx.x * 4 + (threadIdx.x >> 6);
    const int lane = threadIdx.x & 63;
    const int b = row >> 11;  // M = 2048
    const int idx = nao[row];
    const uint4 p = ((const uint4*)(hpack + ((size_t)b * N + idx) * H))[lane];
    float4 v = { unpacksplit(p.x), unpacksplit(p.y), unpacksplit(p.z), unpacksplit(p.w) };
    ((float4*)(out + (size_t)row * H))[lane] = v;
}

__global__ __launch_bounds__(256) void gmean_kernel(
    const float* __restrict__ sel, float* __restrict__ gacc)
{
    const int b = blockIdx.x >> 4;
    const int c = blockIdx.x & 15;
    const int j = threadIdx.x;
    float s = 0.0f;
    const float* base = sel + ((size_t)b * M + (size_t)c * 128) * H + j;
    for (int m = 0; m < 128; ++m) s += base[(size_t)m * H];
    atomicAdd(&gacc[b * H + j], s);
}

__global__ __launch_bounds__(256) void final_kernel(
    const float* __restrict__ gacc, float* __restrict__ out)
{
    const int i = blockIdx.x * 256 + threadIdx.x;
    const size_t sel_sz = (size_t)B * M * H;
    if (i < B * M) {
        out[sel_sz + i] = 1.0f;
    } else {
        const int j = i - B * M;
        out[sel_sz + B * M + j] = tanhf(gacc[j] * (1.0f / (float)M));
    }
}

extern "C" void kernel_launch(void* const* d_in, const int* in_sizes, int n_in,
                              void* d_out, int out_size, void* d_ws, size_t ws_size,
                              hipStream_t stream) {
    const float* emb  = (const float*)d_in[0];
    const int*   nao  = (const int*)d_in[2];
    const int*   ed0  = (const int*)d_in[3];
    const int*   ed1  = (const int*)d_in[4];
    const int*   ed2  = (const int*)d_in[5];
    const int*   ed3  = (const int*)d_in[6];
    const float* W_msg = (const float*)d_in[7];
    const float* b_msg = (const float*)d_in[8];
    const float* W_ih  = (const float*)d_in[9];
    const float* W_hh  = (const float*)d_in[10];
    const float* b_ih  = (const float*)d_in[11];
    const float* b_hh  = (const float*)d_in[12];
    float* out = (float*)d_out;

    const size_t helems = (size_t)B * N * H;       // 8.39M

    // hp ping-pong (2 x 33.55 MB) + medge chunks. CB=4 needs ~137 MB,
    // CB=2 needs ~103 MB.
    const size_t fixed_tail = ((size_t)ET * 16 * 8 * 64 * 8) * 2   // Wmt
                            + ((size_t)6 * 16 * 8 * 64 * 8) * 2    // Wt
                            + (size_t)B * N * 4                    // csrn
                            + (size_t)B * ET * E * 4               // eslot
                            + (size_t)B * H * 4;                   // gacc
    const size_t need4 = helems * 8 + (size_t)4 * ET * E * H * 2 + fixed_tail;
    const int CB = (ws_size >= need4) ? 4 : 2;

    unsigned*       hp0   = (unsigned*)d_ws;                              // 33.55 MB
    unsigned*       hp1   = hp0 + helems;                                 // 33.55 MB
    unsigned short* medge = (unsigned short*)(hp1 + helems);              // CB*16.78 MB
    __bf16*   Wmt   = (__bf16*)(medge + (size_t)CB * ET * E * H);
    __bf16*   Wt    = Wmt + (size_t)ET * 16 * 8 * 64 * 8;
    int*      csrn  = (int*)(Wt + (size_t)6 * 16 * 8 * 64 * 8);
    int*      eslot = csrn + (size_t)B * N;
    float*    gacc  = (float*)(eslot + (size_t)B * ET * E);

    // ---- setup ----
    pack_kernel<<<dim3(helems / 4 / 256), 256, 0, stream>>>(emb, hp0);
    wtrans_msg<<<dim3(128), 256, 0, stream>>>(W_msg, Wmt);
    wtrans_gate<<<dim3(192), 256, 0, stream>>>(W_ih, W_hh, Wt);
    hipMemsetAsync(csrn, 0, (size_t)B * N * sizeof(int), stream);
    countk2<<<dim3(B * ET * E / 256), 256, 0, stream>>>(ed0, ed1, ed2, ed3, csrn);
    scank<<<dim3(B), 256, 0, stream>>>(csrn);
    fillk2<<<dim3(B * ET * E / 256), 256, 0, stream>>>(ed0, ed1, ed2, ed3, csrn, eslot);

    // ---- T iterations, CB-batch chunks, hp ping-pong ----
    // t even: hin=hp0, hout=hp1; t odd: hin=hp1, hout=hp0.
    // T_ITERS=8 -> final h lands in hp0.
    for (int t = 0; t < T_ITERS; ++t) {
        const unsigned* hin  = (t & 1) ? hp1 : hp0;
        unsigned*       hout = (t & 1) ? hp0 : hp1;
        for (int bc = 0; bc < B / CB; ++bc) {
            msgk3<<<dim3(E / 32, CB * ET), 512, 0, stream>>>(
                hin, ed0, ed1, ed2, ed3, eslot, Wmt, b_msg, medge, bc * CB);
            gruk<<<dim3(CB * N / 32 * 2), 512, 0, stream>>>(
                medge, csrn, hin, hout, Wt, b_ih, b_hh, bc * CB);
        }
    }

    // ---- epilogue (final h in hp0) ----
    hipMemsetAsync(gacc, 0, (size_t)B * H * sizeof(float), stream);
    sel_kernel<<<dim3(B * M / 4), 256, 0, stream>>>(hp0, nao, out);
    gmean_kernel<<<dim3(B * 16), 256, 0, stream>>>(out, gacc);
    final_kernel<<<dim3((B * M + B * H) / 256), 256, 0, stream>>>(gacc, out);
}

// Round 15
// 957.940 us; speedup vs baseline: 2.1817x; 1.0750x over previous
//
#include <hip/hip_runtime.h>

#define B 4
#define N 8192
#define H 256
#define E 8192
#define M 2048
#define T_ITERS 8
#define ET 4

typedef __bf16 bf16x8 __attribute__((ext_vector_type(8)));
typedef _Float16 f16x8 __attribute__((ext_vector_type(8)));
typedef float f32x4 __attribute__((ext_vector_type(4)));

__device__ __forceinline__ unsigned short f2bf(float x) {
    unsigned u = __float_as_uint(x);
    u += 0x7fffu + ((u >> 16) & 1u);
    return (unsigned short)(u >> 16);
}
__device__ __forceinline__ unsigned short f2h(float x) {
    union { _Float16 h; unsigned short s; } u;
    u.h = (_Float16)x;
    return u.s;
}
__device__ __forceinline__ f16x8 asf16(bf16x8 v) {
    union { bf16x8 b; f16x8 h; } u; u.b = v; return u.h;
}
__device__ __forceinline__ unsigned packsplit(float x) {
    unsigned hi = f2bf(x);
    float hif = __uint_as_float(hi << 16);
    unsigned lo = f2bf(x - hif);
    return (hi << 16) | lo;
}
__device__ __forceinline__ float unpacksplit(unsigned p) {
    return __uint_as_float(p & 0xffff0000u) + __uint_as_float(p << 16);
}
__device__ __forceinline__ float fsig(float x) { return 1.0f / (1.0f + __expf(-x)); }
__device__ __forceinline__ float ftanh(float x) {
    float cx = fminf(fmaxf(x, -30.0f), 30.0f);
    float t = __expf(2.0f * cx);
    return (t - 1.0f) / (t + 1.0f);
}

__device__ __forceinline__ void unpack8(uint4 a, uint4 b, bf16x8& hi, bf16x8& lo) {
    union U { unsigned u[4]; bf16x8 v; } uh, ul;
    uh.u[0] = (a.x >> 16) | (a.y & 0xffff0000u);
    uh.u[1] = (a.z >> 16) | (a.w & 0xffff0000u);
    uh.u[2] = (b.x >> 16) | (b.y & 0xffff0000u);
    uh.u[3] = (b.z >> 16) | (b.w & 0xffff0000u);
    ul.u[0] = (a.x & 0xffffu) | (a.y << 16);
    ul.u[1] = (a.z & 0xffffu) | (a.w << 16);
    ul.u[2] = (b.x & 0xffffu) | (b.y << 16);
    ul.u[3] = (b.z & 0xffffu) | (b.w << 16);
    hi = uh.v; lo = ul.v;
}

// fp32 -> split bf16 hi/lo pack (initial embedding)
__global__ __launch_bounds__(256) void pack_kernel(
    const float* __restrict__ src, unsigned* __restrict__ dst)
{
    const int i = blockIdx.x * 256 + threadIdx.x;
    const float4 v = ((const float4*)src)[i];
    uint4 o = { packsplit(v.x), packsplit(v.y), packsplit(v.z), packsplit(v.w) };
    ((uint4*)dst)[i] = o;
}

// msg weights -> fragment-major, stored as FP16 bits (pairs with fp16 h
// in msgk3's single-MFMA path; |W|<1/16 so fp16 is more accurate than bf16).
__global__ __launch_bounds__(256) void wtrans_msg(
    const float* __restrict__ W_msg, __bf16* __restrict__ Wmt)
{
    const int f = blockIdx.x * 256 + threadIdx.x;  // 0..32767
    const int ln = f & 63;
    const int t = (f >> 6) & 7;
    const int c16 = (f >> 9) & 15;
    const int e = f >> 13;
    const int col = c16 * 16 + (ln & 15);
    const int k = t * 32 + (ln >> 4) * 8;
    const float* src = W_msg + ((size_t)e * H + col) * H + k;
    const float4 a = *(const float4*)src;
    const float4 b = *(const float4*)(src + 4);
    ushort4 o0 = { f2h(a.x), f2h(a.y), f2h(a.z), f2h(a.w) };
    ushort4 o1 = { f2h(b.x), f2h(b.y), f2h(b.z), f2h(b.w) };
    *(ushort4*)(Wmt + (size_t)f * 8) = o0;
    *(ushort4*)(Wmt + (size_t)f * 8 + 4) = o1;
}

// gate weights -> fragment-major. g 0..2: W_ih r,z,n stored as FP16 bits
// (pairs with fp16 x in gruk's single-MFMA ih path). g 3..5: W_hh r,z,n
// as bf16 (pairs with split-bf16 h).
__global__ __launch_bounds__(256) void wtrans_gate(
    const float* __restrict__ W_ih, const float* __restrict__ W_hh,
    __bf16* __restrict__ Wt)
{
    const int f = blockIdx.x * 256 + threadIdx.x;  // 0..49151
    const int ln = f & 63;
    const int t = (f >> 6) & 7;
    const int c16 = (f >> 9) & 15;
    const int g = f >> 13;
    const int col = c16 * 16 + (ln & 15);
    const int k = t * 32 + (ln >> 4) * 8;
    const float* src = (g < 3) ? (W_ih + ((size_t)g * H + col) * H + k)
                               : (W_hh + ((size_t)(g - 3) * H + col) * H + k);
    const float4 a = *(const float4*)src;
    const float4 b = *(const float4*)(src + 4);
    ushort4 o0, o1;
    if (g < 3) {
        o0 = (ushort4){ f2h(a.x), f2h(a.y), f2h(a.z), f2h(a.w) };
        o1 = (ushort4){ f2h(b.x), f2h(b.y), f2h(b.z), f2h(b.w) };
    } else {
        o0 = (ushort4){ f2bf(a.x), f2bf(a.y), f2bf(a.z), f2bf(a.w) };
        o1 = (ushort4){ f2bf(b.x), f2bf(b.y), f2bf(b.z), f2bf(b.w) };
    }
    *(ushort4*)(Wt + (size_t)f * 8) = o0;
    *(ushort4*)(Wt + (size_t)f * 8 + 4) = o1;
}

// ---- combined CSR build: one list per (b, node), all 4 edge-types ----
__global__ __launch_bounds__(256) void countk2(
    const int* __restrict__ ed0, const int* __restrict__ ed1,
    const int* __restrict__ ed2, const int* __restrict__ ed3,
    int* __restrict__ csrn)
{
    const int i = blockIdx.x * 256 + threadIdx.x;  // 0..B*ET*E-1
    const int edge = i & (E - 1);
    const int be = i >> 13;
    const int b = be >> 2, e = be & 3;
    const int* ed = (e == 0) ? ed0 : (e == 1) ? ed1 : (e == 2) ? ed2 : ed3;
    const int tgt = ed[((size_t)b * E + edge) * 2 + 1];
    atomicAdd(&csrn[(size_t)b * N + tgt], 1);
}

__global__ __launch_bounds__(256) void scank(int* __restrict__ csr)
{
    int* d = csr + (size_t)blockIdx.x * N;
    const int t = threadIdx.x;
    __shared__ int part[256];
    int loc[32];
    const int base = t * 32;
    int s = 0;
    #pragma unroll
    for (int i = 0; i < 32; ++i) { loc[i] = d[base + i]; s += loc[i]; }
    part[t] = s;
    __syncthreads();
    if (t == 0) { int a = 0; for (int i = 0; i < 256; ++i) { int v = part[i]; part[i] = a; a += v; } }
    __syncthreads();
    int a = part[t];
    #pragma unroll
    for (int i = 0; i < 32; ++i) { d[base + i] = a; a += loc[i]; }
}

__global__ __launch_bounds__(256) void fillk2(
    const int* __restrict__ ed0, const int* __restrict__ ed1,
    const int* __restrict__ ed2, const int* __restrict__ ed3,
    int* __restrict__ csrn, int* __restrict__ eslot)
{
    const int i = blockIdx.x * 256 + threadIdx.x;
    const int edge = i & (E - 1);
    const int be = i >> 13;
    const int b = be >> 2, e = be & 3;
    const int* ed = (e == 0) ? ed0 : (e == 1) ? ed1 : (e == 2) ? ed2 : ed3;
    const int tgt = ed[((size_t)b * E + edge) * 2 + 1];
    const int pos = atomicAdd(&csrn[(size_t)b * N + tgt], 1);
    eslot[i] = pos;
}

// msg GEMM v4: single-plane FP16 (R11's gruk x-side move applied here).
// h staged as fp16 (unpacksplit -> f2h; |h|<~6 so range-safe; 2^-11 rep
// error << medge's bf16 output quantization 2^-8), Wmt fp16 ->
// 32 mfma_f32_16x16x32_f16 per wave instead of 64 bf16 MFMAs, LDS 16.1KB.
// medge output stays bf16 (f2bf) so gruk is untouched.
__global__ __launch_bounds__(512, 4) void msgk3(
    const unsigned* __restrict__ hp,
    const int* __restrict__ ed0, const int* __restrict__ ed1,
    const int* __restrict__ ed2, const int* __restrict__ ed3,
    const int* __restrict__ eslot,
    const __bf16* __restrict__ Wmt, const float* __restrict__ b_msg,
    unsigned short* __restrict__ medge, const int b0)
{
    __shared__ __bf16 sS[32 * 256];      // single fp16 plane (bit container)
    __shared__ int s_slot[32];
    const int tid = threadIdx.x;
    const int by = blockIdx.y;           // 0..CB*ET-1
    const int bl = by >> 2, e = by & 3;
    const int b = b0 + bl;
    const int* ed = (e == 0) ? ed0 : (e == 1) ? ed1 : (e == 2) ? ed2 : ed3;
    const int row0 = blockIdx.x * 32;

    const int wv = tid >> 6, ln = tid & 63, lq = ln >> 4, lm = ln & 15;
    const int c16a = wv * 2;             // wave cols [wv*32, wv*32+32)

    // early weight preload for ks=0 (L2 latency overlaps the h gather)
    const __bf16* wb = Wmt + (size_t)ln * 8;
    bf16x8 Wc[2], Wn[2];
    #pragma unroll
    for (int nt = 0; nt < 2; ++nt)
        Wc[nt] = *(const bf16x8*)(wb + (size_t)((e * 16 + c16a + nt) * 8) * 512);

    if (tid < 32) s_slot[tid] = eslot[(size_t)(b * ET + e) * E + row0 + tid];

    // ---- staging: thread -> row tid>>4, k-chunks {seg, seg+16}; h -> fp16 ----
    {
        const int r = tid >> 4;
        const int seg = tid & 15;
        const int src = ed[((size_t)b * E + row0 + r) * 2];
        const unsigned* hrow = hp + ((size_t)b * N + src) * H;
        #pragma unroll
        for (int cc = 0; cc < 2; ++cc) {
            const int c = seg + cc * 16;   // k-chunk index (k = c*8)
            const uint4 ha = *(const uint4*)(hrow + c * 8);
            const uint4 hb = *(const uint4*)(hrow + c * 8 + 4);
            const unsigned w[8] = { ha.x, ha.y, ha.z, ha.w, hb.x, hb.y, hb.z, hb.w };
            union Ux { unsigned short us[8]; bf16x8 v; } xf;
            #pragma unroll
            for (int j = 0; j < 8; ++j)
                xf.us[j] = f2h(unpacksplit(w[j]));
            const int sc = c ^ (r & 7);
            *(bf16x8*)(sS + r * 256 + sc * 8) = xf.v;
        }
    }
    __syncthreads();

    f32x4 zero = {0.f, 0.f, 0.f, 0.f};
    f32x4 acc[2][2];  // [nt][mt]
    #pragma unroll
    for (int nt = 0; nt < 2; ++nt) { acc[nt][0] = zero; acc[nt][1] = zero; }

    #pragma unroll
    for (int ks = 0; ks < 8; ++ks) {
        if (ks < 7) {
            #pragma unroll
            for (int nt = 0; nt < 2; ++nt)
                Wn[nt] = *(const bf16x8*)(wb + (size_t)((e * 16 + c16a + nt) * 8 + ks + 1) * 512);
        }
        #pragma unroll
        for (int mt = 0; mt < 2; ++mt) {
            const int rr = mt * 16 + lm;
            const int sc = (ks * 4 + lq) ^ (rr & 7);
            const bf16x8 af = *(const bf16x8*)(sS + rr * 256 + sc * 8);
            #pragma unroll
            for (int nt = 0; nt < 2; ++nt)
                acc[nt][mt] = __builtin_amdgcn_mfma_f32_16x16x32_f16(
                    asf16(af), asf16(Wc[nt]), acc[nt][mt], 0, 0, 0);
        }
        #pragma unroll
        for (int nt = 0; nt < 2; ++nt) Wc[nt] = Wn[nt];
    }

    unsigned short* mb = medge + (size_t)bl * (ET * E) * H;
    #pragma unroll
    for (int nt = 0; nt < 2; ++nt) {
        const int col = (c16a + nt) * 16 + lm;
        const float bias = b_msg[e * H + col];
        #pragma unroll
        for (int mt = 0; mt < 2; ++mt)
            #pragma unroll
            for (int rr = 0; rr < 4; ++rr) {
                const int slot = s_slot[mt * 16 + lq * 4 + rr];
                mb[(size_t)slot * H + col] = f2bf(acc[nt][mt][rr] + bias);
            }
    }
}

// Fused GRU v12r (exact R11-verified body, ~69us): fp16 x-plane single-MFMA
// ih path, bf16 medge gather with fp32 accumulation, hold prefetch, hp
// ping-pong, XCD-pairing remap. __launch_bounds__(512, 4): this kernel's
// working set is ~112 regs/wave (64 arch + 48 acc) -> 4 waves/SIMD is the
// occupancy ceiling; (512,6) forced VGPR=40 + 562MB of spill traffic (R13).
__global__ __launch_bounds__(512, 4) void gruk(
    const unsigned short* __restrict__ medge, const int* __restrict__ csrn,
    const unsigned* __restrict__ hin, unsigned* __restrict__ hout,
    const __bf16* __restrict__ Wt,
    const float* __restrict__ b_ih, const float* __restrict__ b_hh,
    const int b0)
{
    __shared__ __bf16 sA[3 * 32 * 256];  // 49152 B; planes: x16 / hhi / hlo

    const int tid = threadIdx.x;
    const int g = blockIdx.x;
    const int R = gridDim.x >> 1;                      // rowblks this dispatch
    const int s = g >> 3;
    const int rowblk = (g & 7) * (R >> 3) + (s >> 1);  // 0..R-1
    const int ch = s & 1;                              // col half: [ch*128, +128)
    const int lrow0 = rowblk * 32;                     // chunk-local row base
    const size_t grow0 = (size_t)b0 * N + lrow0;       // global row base

    const int wv = tid >> 6, ln = tid & 63, lq = ln >> 4, lm = ln & 15;
    const int c16 = ch * 8 + wv;                       // wave's single c16 tile
    const int col = c16 * 16 + lm;

    // ---- staging with fused CSR gather: thread -> row tid>>4, 16 k @ (tid&15)*16
    {
        const int r = tid >> 4;
        const int k0 = (tid & 15) * 16;
        const int local = lrow0 + r;
        const int bl = local >> 13;                    // batch within chunk
        const int nn = local & (N - 1);
        const int bb = b0 + bl;
        const int end = csrn[(size_t)bb * N + nn];
        const int start = nn ? csrn[(size_t)bb * N + nn - 1] : 0;

        // independent h-row loads issued BEFORE the gather loop: their
        // ~L2/L3 latency hides under the CSR gather's scattered reads.
        const unsigned* hr = hin + (grow0 + r) * H + k0;
        const uint4 h0 = ((const uint4*)hr)[0];
        const uint4 h1 = ((const uint4*)hr)[1];
        const uint4 h2 = ((const uint4*)hr)[2];
        const uint4 h3 = ((const uint4*)hr)[3];

        float xs[16];
        #pragma unroll
        for (int j = 0; j < 16; ++j) xs[j] = 0.f;

        const unsigned* mbase = (const unsigned*)medge
            + (size_t)bl * (ET * E) * (H / 2) + (k0 >> 1);

        int i = start;
        // 4-edge batches: 8 x 16B loads issued before any accumulation.
        for (; i + 4 <= end; i += 4) {
            uint4 q[8];
            #pragma unroll
            for (int ee = 0; ee < 4; ++ee) {
                const uint4* mr = (const uint4*)(mbase + (size_t)(i + ee) * (H / 2));
                q[ee * 2 + 0] = mr[0];
                q[ee * 2 + 1] = mr[1];
            }
            #pragma unroll
            for (int qi = 0; qi < 8; ++qi) {
                const int eb = (qi & 1) * 8;
                const unsigned pw[4] = { q[qi].x, q[qi].y, q[qi].z, q[qi].w };
                #pragma unroll
                for (int j = 0; j < 4; ++j) {
                    xs[eb + 2 * j]     += __uint_as_float(pw[j] << 16);
                    xs[eb + 2 * j + 1] += __uint_as_float(pw[j] & 0xffff0000u);
                }
            }
        }
        for (; i < end; ++i) {
            const uint4* mr = (const uint4*)(mbase + (size_t)i * (H / 2));
            uint4 q[2];
            q[0] = mr[0]; q[1] = mr[1];
            #pragma unroll
            for (int qi = 0; qi < 2; ++qi) {
                const int eb = qi * 8;
                const unsigned pw[4] = { q[qi].x, q[qi].y, q[qi].z, q[qi].w };
                #pragma unroll
                for (int j = 0; j < 4; ++j) {
                    xs[eb + 2 * j]     += __uint_as_float(pw[j] << 16);
                    xs[eb + 2 * j + 1] += __uint_as_float(pw[j] & 0xffff0000u);
                }
            }
        }

        #pragma unroll
        for (int cc = 0; cc < 2; ++cc) {
            const uint4 ha = cc ? h2 : h0;
            const uint4 hb = cc ? h3 : h1;
            bf16x8 hhi, hlo;
            unpack8(ha, hb, hhi, hlo);
            union Ux { unsigned short us[8]; bf16x8 v; } xf;
            #pragma unroll
            for (int j = 0; j < 8; ++j)
                xf.us[j] = f2h(xs[cc * 8 + j]);
            const int sc = ((k0 >> 3) + cc) ^ (r & 7);
            __bf16* base = sA + r * 256 + sc * 8;
            *(bf16x8*)(base)          = xf.v;   // x plane (fp16 bits)
            *(bf16x8*)(base + 8192)   = hhi;
            *(bf16x8*)(base + 16384)  = hlo;
        }
    }

    // ---- weight preload for ks=0 (issues before barrier) ----
    const __bf16* wb = Wt + (size_t)ln * 8;
    bf16x8 Wc[6], Wn[6];
    #pragma unroll
    for (int g2 = 0; g2 < 6; ++g2)
        Wc[g2] = *(const bf16x8*)(wb + (size_t)((g2 * 16 + c16) * 8) * 512);

    // ---- hold prefetch: the 8 h_t words this lane's epilogue needs,
    // loaded as packed-split u32 from hin (L2-warm); latency hides under
    // the K-loop. Safe vs other blocks: all writes go to hout.
    unsigned holdw[8];
    #pragma unroll
    for (int mt = 0; mt < 2; ++mt)
        #pragma unroll
        for (int rr = 0; rr < 4; ++rr)
            holdw[mt * 4 + rr] = hin[(grow0 + mt * 16 + lq * 4 + rr) * H + col];

    __syncthreads();

    f32x4 zero = {0.f, 0.f, 0.f, 0.f};
    f32x4 acc[6][2];  // [g][mt]
    #pragma unroll
    for (int g2 = 0; g2 < 6; ++g2) { acc[g2][0] = zero; acc[g2][1] = zero; }

    #pragma unroll
    for (int ks = 0; ks < 8; ++ks) {
        if (ks < 7) {
            #pragma unroll
            for (int g2 = 0; g2 < 6; ++g2)
                Wn[g2] = *(const bf16x8*)(wb + (size_t)((g2 * 16 + c16) * 8 + ks + 1) * 512);
        }
        #pragma unroll
        for (int mt = 0; mt < 2; ++mt) {
            const int rr = mt * 16 + lm;
            const int sc = (ks * 4 + lq) ^ (rr & 7);
            const __bf16* ab = sA + rr * 256 + sc * 8;
            const bf16x8 xf  = *(const bf16x8*)(ab);
            const bf16x8 hhi = *(const bf16x8*)(ab + 8192);
            const bf16x8 hlo = *(const bf16x8*)(ab + 16384);
            #pragma unroll
            for (int g2 = 0; g2 < 3; ++g2)
                acc[g2][mt] = __builtin_amdgcn_mfma_f32_16x16x32_f16(
                    asf16(xf), asf16(Wc[g2]), acc[g2][mt], 0, 0, 0);
            #pragma unroll
            for (int g2 = 3; g2 < 6; ++g2) {
                acc[g2][mt] = __builtin_amdgcn_mfma_f32_16x16x32_bf16(hhi, Wc[g2], acc[g2][mt], 0, 0, 0);
                acc[g2][mt] = __builtin_amdgcn_mfma_f32_16x16x32_bf16(hlo, Wc[g2], acc[g2][mt], 0, 0, 0);
            }
        }
        #pragma unroll
        for (int g2 = 0; g2 < 6; ++g2) Wc[g2] = Wn[g2];
    }

    // ---- fused gates; hold from prefetched registers; store to hout ----
    {
        const float bi_r = b_ih[col], bi_z = b_ih[H + col], bi_n = b_ih[2 * H + col];
        const float bh_r = b_hh[col], bh_z = b_hh[H + col], bh_n = b_hh[2 * H + col];
        #pragma unroll
        for (int mt = 0; mt < 2; ++mt) {
            #pragma unroll
            for (int rr = 0; rr < 4; ++rr) {
                const int lrow = mt * 16 + lq * 4 + rr;  // block-local row
                const float hold = unpacksplit(holdw[mt * 4 + rr]);
                const float rg = fsig(acc[0][mt][rr] + bi_r + acc[3][mt][rr] + bh_r);
                const float zg = fsig(acc[1][mt][rr] + bi_z + acc[4][mt][rr] + bh_z);
                const float ng = ftanh(acc[2][mt][rr] + bi_n + rg * (acc[5][mt][rr] + bh_n));
                const float o = (1.0f - zg) * ng + zg * hold;
                hout[(grow0 + lrow) * H + col] = packsplit(o);
            }
        }
    }
}

__global__ __launch_bounds__(256) void sel_kernel(
    const unsigned* __restrict__ hpack, const int* __restrict__ nao,
    float* __restrict__ out)
{
    const int row = blockIdx.x * 4 + (threadIdx.x >> 6);
    const int lane = threadIdx.x & 63;
    const int b = row >> 11;  // M = 2048
    const int idx = nao[row];
    const uint4 p = ((const uint4*)(hpack + ((size_t)b * N + idx) * H))[lane];
    float4 v = { unpacksplit(p.x), unpacksplit(p.y), unpacksplit(p.z), unpacksplit(p.w) };
    ((float4*)(out + (size_t)row * H))[lane] = v;
}

__global__ __launch_bounds__(256) void gmean_kernel(
    const float* __restrict__ sel, float* __restrict__ gacc)
{
    const int b = blockIdx.x >> 4;
    const int c = blockIdx.x & 15;
    const int j = threadIdx.x;
    float s = 0.0f;
    const float* base = sel + ((size_t)b * M + (size_t)c * 128) * H + j;
    for (int m = 0; m < 128; ++m) s += base[(size_t)m * H];
    atomicAdd(&gacc[b * H + j], s);
}

__global__ __launch_bounds__(256) void final_kernel(
    const float* __restrict__ gacc, float* __restrict__ out)
{
    const int i = blockIdx.x * 256 + threadIdx.x;
    const size_t sel_sz = (size_t)B * M * H;
    if (i < B * M) {
        out[sel_sz + i] = 1.0f;
    } else {
        const int j = i - B * M;
        out[sel_sz + B * M + j] = tanhf(gacc[j] * (1.0f / (float)M));
    }
}

extern "C" void kernel_launch(void* const* d_in, const int* in_sizes, int n_in,
                              void* d_out, int out_size, void* d_ws, size_t ws_size,
                              hipStream_t stream) {
    const float* emb  = (const float*)d_in[0];
    const int*   nao  = (const int*)d_in[2];
    const int*   ed0  = (const int*)d_in[3];
    const int*   ed1  = (const int*)d_in[4];
    const int*   ed2  = (const int*)d_in[5];
    const int*   ed3  = (const int*)d_in[6];
    const float* W_msg = (const float*)d_in[7];
    const float* b_msg = (const float*)d_in[8];
    const float* W_ih  = (const float*)d_in[9];
    const float* W_hh  = (const float*)d_in[10];
    const float* b_ih  = (const float*)d_in[11];
    const float* b_hh  = (const float*)d_in[12];
    float* out = (float*)d_out;

    const size_t helems = (size_t)B * N * H;       // 8.39M

    // hp ping-pong (2 x 33.55 MB) + medge chunks. CB=4 needs ~137 MB,
    // CB=2 needs ~103 MB.
    const size_t fixed_tail = ((size_t)ET * 16 * 8 * 64 * 8) * 2   // Wmt
                            + ((size_t)6 * 16 * 8 * 64 * 8) * 2    // Wt
                            + (size_t)B * N * 4                    // csrn
                            + (size_t)B * ET * E * 4               // eslot
                            + (size_t)B * H * 4;                   // gacc
    const size_t need4 = helems * 8 + (size_t)4 * ET * E * H * 2 + fixed_tail;
    const int CB = (ws_size >= need4) ? 4 : 2;

    unsigned*       hp0   = (unsigned*)d_ws;                              // 33.55 MB
    unsigned*       hp1   = hp0 + helems;                                 // 33.55 MB
    unsigned short* medge = (unsigned short*)(hp1 + helems);              // CB*16.78 MB
    __bf16*   Wmt   = (__bf16*)(medge + (size_t)CB * ET * E * H);
    __bf16*   Wt    = Wmt + (size_t)ET * 16 * 8 * 64 * 8;
    int*      csrn  = (int*)(Wt + (size_t)6 * 16 * 8 * 64 * 8);
    int*      eslot = csrn + (size_t)B * N;
    float*    gacc  = (float*)(eslot + (size_t)B * ET * E);

    // ---- setup ----
    pack_kernel<<<dim3(helems / 4 / 256), 256, 0, stream>>>(emb, hp0);
    wtrans_msg<<<dim3(128), 256, 0, stream>>>(W_msg, Wmt);
    wtrans_gate<<<dim3(192), 256, 0, stream>>>(W_ih, W_hh, Wt);
    hipMemsetAsync(csrn, 0, (size_t)B * N * sizeof(int), stream);
    countk2<<<dim3(B * ET * E / 256), 256, 0, stream>>>(ed0, ed1, ed2, ed3, csrn);
    scank<<<dim3(B), 256, 0, stream>>>(csrn);
    fillk2<<<dim3(B * ET * E / 256), 256, 0, stream>>>(ed0, ed1, ed2, ed3, csrn, eslot);

    // ---- T iterations, CB-batch chunks, hp ping-pong ----
    // t even: hin=hp0, hout=hp1; t odd: hin=hp1, hout=hp0.
    // T_ITERS=8 -> final h lands in hp0.
    for (int t = 0; t < T_ITERS; ++t) {
        const unsigned* hin  = (t & 1) ? hp1 : hp0;
        unsigned*       hout = (t & 1) ? hp0 : hp1;
        for (int bc = 0; bc < B / CB; ++bc) {
            msgk3<<<dim3(E / 32, CB * ET), 512, 0, stream>>>(
                hin, ed0, ed1, ed2, ed3, eslot, Wmt, b_msg, medge, bc * CB);
            gruk<<<dim3(CB * N / 32 * 2), 512, 0, stream>>>(
                medge, csrn, hin, hout, Wt, b_ih, b_hh, bc * CB);
        }
    }

    // ---- epilogue (final h in hp0) ----
    hipMemsetAsync(gacc, 0, (size_t)B * H * sizeof(float), stream);
    sel_kernel<<<dim3(B * M / 4), 256, 0, stream>>>(hp0, nao, out);
    gmean_kernel<<<dim3(B * 16), 256, 0, stream>>>(out, gacc);
    final_kernel<<<dim3((B * M + B * H) / 256), 256, 0, stream>>>(gacc, out);
}